// Round 1
// baseline (197.090 us; speedup 1.0000x reference)
//
#include <hip/hip_runtime.h>

// FWEnergyGAD: element-wise double-well energy + forces + GAD direction +
// 2x2 Hessian eigendecomposition (closed form).
//
// Outputs concatenated flat in return order (n = B):
//   [0,     n)   energy
//   [n,    3n)   forces      (B,2)
//   [3n,   5n)   energy_grad (B,2)
//   [5n,   9n)   hessian     (B,2,2)
//   [9n,  10n)   eigenval 0  (smaller)
//   [10n, 11n)   eigenval 1  (larger)

__global__ __launch_bounds__(256) void fw_energy_gad_kernel(
    const float2* __restrict__ in, float* __restrict__ out, int n) {
    int i = blockIdx.x * blockDim.x + threadIdx.x;
    if (i >= n) return;

    const float BETA = 0.1f;

    float2 p = in[i];
    float u = p.x - 0.5f;
    float v = p.y - 0.5f;
    float uu = u * u;
    float vv = v * v;
    float a = uu - 1.0f;   // u^2 - 1
    float b = vv - 1.0f;   // v^2 - 1

    float energy = a * a + b * b + BETA * u * v;

    float gx = 4.0f * u * a + BETA * v;
    float gy = 4.0f * v * b + BETA * u;
    float fx = -gx;
    float fy = -gy;

    float hxx = 12.0f * uu - 4.0f;
    float hyy = 12.0f * vv - 4.0f;
    // hxy = BETA (constant)

    // 2x2 symmetric eigendecomposition, closed form.
    float d = 0.5f * (hxx - hyy);
    float m = 0.5f * (hxx + hyy);
    float r = sqrtf(d * d + BETA * BETA);   // r >= 0.1, never degenerate
    float l0 = m - r;                        // smaller eigenvalue
    float l1 = m + r;                        // larger eigenvalue

    // Eigenvector of l0, branch chosen to avoid cancellation (d can be ~380
    // in magnitude vs hxy=0.1; the other branch computes r-|d| which is
    // catastrophic in fp32).
    float wx, wy;
    if (d >= 0.0f) {
        wx = BETA;
        wy = -(d + r);
    } else {
        wx = d - r;
        wy = BETA;
    }
    float n2 = wx * wx + wy * wy;            // >= 0.01

    // gad = -f + 2 (f.w_hat) w_hat ; sign of w irrelevant (quadratic).
    float fd = fx * wx + fy * wy;
    float s = 2.0f * fd / n2;
    float gadx = -fx + s * wx;
    float gady = -fy + s * wy;

    float prod = l0 * l1;                    // matches reference's eigval product
    float gmag = sqrtf(gadx * gadx + gady * gady);
    if (prod > 0.0f && gmag < 1.0f) {
        float inv = 1.0f / fmaxf(gmag, 1e-30f);
        gadx *= inv;
        gady *= inv;
    }
    // TAU = 1.0 -> energy_grad == gad

    size_t N = (size_t)n;
    float*  e_out = out;
    float2* f_out = (float2*)(out + N);
    float2* g_out = (float2*)(out + 3 * N);
    float4* h_out = (float4*)(out + 5 * N);
    float*  l0_out = out + 9 * N;
    float*  l1_out = out + 10 * N;

    e_out[i] = energy;
    f_out[i] = make_float2(fx, fy);
    g_out[i] = make_float2(gadx, gady);
    h_out[i] = make_float4(hxx, BETA, BETA, hyy);
    l0_out[i] = l0;
    l1_out[i] = l1;
}

extern "C" void kernel_launch(void* const* d_in, const int* in_sizes, int n_in,
                              void* d_out, int out_size, void* d_ws, size_t ws_size,
                              hipStream_t stream) {
    const float2* in = (const float2*)d_in[0];
    float* out = (float*)d_out;
    int n = in_sizes[0] / 2;   // B elements, each (x, y)

    int block = 256;
    int grid = (n + block - 1) / block;
    fw_energy_gad_kernel<<<grid, block, 0, stream>>>(in, out, n);
}